// Round 4
// baseline (33.704 us; speedup 1.0000x reference)
//
#include <hip/hip_runtime.h>
#include <math.h>

// Kaldi LinearResample 16000 -> 22050, LPW=6.
// P=441 phases, STRIDE=320, W=13 taps, tot = 441*3000.
// GPW=3 consecutive phases per thread: one aligned 20-float window (5x float4)
// feeds 3 outputs. Per-phase weights re-expressed as 20-tap rows relative to
// the group's aligned base, 15 float4 in registers, reused over MPT m-steps.
// R3 changes: block-level edge hoisting (interior blocks branch-free),
// running-pointer addressing, 2-stage load pipeline, packed 3-float stores.
#define ORIG_F 16000
#define NEW_F  22050
#define LPW    6
#define P      441
#define STRIDE 320
#define W      13
#define GPW    3
#define NG     147      // 441/3
#define W20    20
#define MPT    12       // m-steps per thread
#define MCH    250      // 3000/MPT
#define BATCH  8

#ifndef M_PI
#define M_PI 3.14159265358979323846
#endif

__device__ __forceinline__ double kaldi_fi(int p, double* out_t) {
    const double cutoff = 0.99 * 0.5 * (double)ORIG_F;
    const double ww = (double)LPW / (2.0 * cutoff);
    double ot = (double)p / (double)NEW_F;
    *out_t = ot;
    return ceil((ot - ww) * (double)ORIG_F);
}

// One thread per (phase, padded tap j in [0,20)): w20[p][j] = weight applied
// to x[gab[g]+j] for phase p (0 outside 13-tap support); gab[g]=fi[3g]&~3.
__global__ void build_table20_kernel(float* __restrict__ w20, int* __restrict__ gab) {
    int idx = blockIdx.x * blockDim.x + threadIdx.x;
    if (idx >= P * W20) return;
    int p = idx / W20;
    int j = idx - p * W20;
    const double cutoff = 0.99 * 0.5 * (double)ORIG_F;
    const double ww = (double)LPW / (2.0 * cutoff);
    double out_t, out_t0;
    double min_i = kaldi_fi(p, &out_t);
    int fi = (int)min_i;
    int p0 = (p / GPW) * GPW;
    int fi0 = (int)kaldi_fi(p0, &out_t0);
    int ab = fi0 & ~3;
    if (j == 0 && p == p0) gab[p / GPW] = ab;
    int jt = ab + j - fi;
    float wf = 0.f;
    if (jt >= 0 && jt < W) {
        double dt = (min_i + (double)jt) / (double)ORIG_F - out_t;
        double wv = 0.0;
        if (fabs(dt) < ww) {
            wv = 0.5 * (1.0 + cos(2.0 * M_PI * cutoff / (double)LPW * dt));
            if (dt != 0.0) wv *= sin(2.0 * M_PI * cutoff * dt) / (M_PI * dt);
            else           wv *= 2.0 * cutoff;
        }
        wv /= (double)ORIG_F;
        wf = (float)wv;
    }
    w20[p * W20 + j] = wf;
}

__device__ __forceinline__ float dot20(const float4& x0, const float4& x1,
                                       const float4& x2, const float4& x3,
                                       const float4& x4, const float4* w) {
    return x0.x*w[0].x + x0.y*w[0].y + x0.z*w[0].z + x0.w*w[0].w
         + x1.x*w[1].x + x1.y*w[1].y + x1.z*w[1].z + x1.w*w[1].w
         + x2.x*w[2].x + x2.y*w[2].y + x2.z*w[2].z + x2.w*w[2].w
         + x3.x*w[3].x + x3.y*w[3].y + x3.z*w[3].z + x3.w*w[3].w
         + x4.x*w[4].x + x4.y*w[4].y + x4.z*w[4].z + x4.w*w[4].w;
}

__device__ __forceinline__ void load_guarded(const float* __restrict__ xb, int base,
                                             int n, unsigned safe_lim,
                                             float4& x0, float4& x1, float4& x2,
                                             float4& x3, float4& x4) {
    if ((unsigned)base <= safe_lim) {
        const float4* q = (const float4*)(xb + base);
        x0 = q[0]; x1 = q[1]; x2 = q[2]; x3 = q[3]; x4 = q[4];
    } else {
        float xs[W20];
        #pragma unroll
        for (int j = 0; j < W20; ++j) {
            int ii = base + j;
            xs[j] = (ii >= 0 && ii < n) ? xb[ii] : 0.f;
        }
        x0 = make_float4(xs[0], xs[1], xs[2], xs[3]);
        x1 = make_float4(xs[4], xs[5], xs[6], xs[7]);
        x2 = make_float4(xs[8], xs[9], xs[10], xs[11]);
        x3 = make_float4(xs[12], xs[13], xs[14], xs[15]);
        x4 = make_float4(xs[16], xs[17], xs[18], xs[19]);
    }
}

// Thread owns (b, mc, g): 3 outputs x MPT m-steps. Lanes = consecutive g ->
// overlapping loads, dense packed stores (dwordx3 per thread).
__global__ __launch_bounds__(256) void resample4_kernel(
    const float* __restrict__ x, const float* __restrict__ w20,
    const int* __restrict__ gab, float* __restrict__ out,
    int n, int tot)
{
    int tid = blockIdx.x * blockDim.x + threadIdx.x;
    int g    = tid % NG;
    int rest = tid / NG;
    int mc   = rest % MCH;
    int b    = rest / MCH;
    if (b >= BATCH) return;

    const float* __restrict__ xb = x + (size_t)b * n;
    float* __restrict__ ob = out + (size_t)b * tot;

    const float4* wp = (const float4*)(w20 + g * (GPW * W20));
    float4 w[15];
    #pragma unroll
    for (int i = 0; i < 15; ++i) w[i] = wp[i];

    const int ab = gab[g];
    const int m0 = mc * MPT;
    int base = ab + m0 * STRIDE;
    int t    = m0 * P + g * GPW;

    if (mc != 0 && mc != MCH - 1) {
        // Interior: every window is fully in-bounds. Branch-free pipeline.
        const float* xp = xb + base;
        const float4* q = (const float4*)xp;
        float4 c0 = q[0], c1 = q[1], c2 = q[2], c3 = q[3], c4 = q[4];
        #pragma unroll
        for (int k = 0; k < MPT; ++k) {
            float4 n0, n1, n2, n3, n4;
            if (k < MPT - 1) {
                const float4* qn = (const float4*)(xp + STRIDE);
                n0 = qn[0]; n1 = qn[1]; n2 = qn[2]; n3 = qn[3]; n4 = qn[4];
            }
            float a0 = dot20(c0, c1, c2, c3, c4, &w[0]);
            float a1 = dot20(c0, c1, c2, c3, c4, &w[5]);
            float a2 = dot20(c0, c1, c2, c3, c4, &w[10]);
            ob[t] = a0; ob[t + 1] = a1; ob[t + 2] = a2;   // merges to dwordx3
            c0 = n0; c1 = n1; c2 = n2; c3 = n3; c4 = n4;
            xp += STRIDE; t += P;
        }
    } else {
        // Edge chunk: only m==0 (left pad) / m==2999 (right pad) need guards.
        const unsigned safe_lim = (unsigned)(n - W20);
        float4 c0, c1, c2, c3, c4;
        load_guarded(xb, base, n, safe_lim, c0, c1, c2, c3, c4);
        for (int k = 0; k < MPT; ++k) {
            float4 n0, n1, n2, n3, n4;
            if (k < MPT - 1)
                load_guarded(xb, base + STRIDE, n, safe_lim, n0, n1, n2, n3, n4);
            float a0 = dot20(c0, c1, c2, c3, c4, &w[0]);
            float a1 = dot20(c0, c1, c2, c3, c4, &w[1 * 5]);
            float a2 = dot20(c0, c1, c2, c3, c4, &w[2 * 5]);
            ob[t] = a0; ob[t + 1] = a1; ob[t + 2] = a2;
            c0 = n0; c1 = n1; c2 = n2; c3 = n3; c4 = n4;
            base += STRIDE; t += P;
        }
    }
}

extern "C" void kernel_launch(void* const* d_in, const int* in_sizes, int n_in,
                              void* d_out, int out_size, void* d_ws, size_t ws_size,
                              hipStream_t stream) {
    const float* x = (const float*)d_in[0];
    float* out = (float*)d_out;

    const int n = in_sizes[0] / BATCH;     // 960000

    // Kaldi GetNumOutputSamples
    long long interval = (long long)n * P;
    long long last = interval / STRIDE;
    if (last * STRIDE == interval) last -= 1;
    const int tot = (int)(last + 1);       // 1,323,000 = 441*3000

    float* w20 = (float*)d_ws;
    int*   gab = (int*)((char*)d_ws + (size_t)P * W20 * sizeof(float));

    build_table20_kernel<<<(P * W20 + 255) / 256, 256, 0, stream>>>(w20, gab);

    const long long nthreads = (long long)BATCH * MCH * NG;   // 294,000
    const int nblk = (int)((nthreads + 255) / 256);
    resample4_kernel<<<nblk, 256, 0, stream>>>(x, w20, gab, out, n, tot);
}